// Round 16
// baseline (705.938 us; speedup 1.0000x reference)
//
#include <hip/hip_runtime.h>

typedef unsigned short u16;
typedef unsigned int u32;
typedef short bhalf8 __attribute__((ext_vector_type(8)));
typedef float f32x4 __attribute__((ext_vector_type(4)));

#define S_LEN 4096
#define NSEG 30

__device__ __forceinline__ float b2f(u16 h){ return __uint_as_float(((u32)h) << 16); }
__device__ __forceinline__ u16 f2b(float f){
  u32 u = __float_as_uint(f);
  return (u16)((u + 0x7FFFu + ((u >> 16) & 1u)) >> 16);
}
__device__ __forceinline__ u32 cvtpk(float a, float b){
  u32 r; asm("v_cvt_pk_bf16_f32 %0, %1, %2" : "=v"(r) : "v"(a), "v"(b)); return r;
}
__device__ __forceinline__ void unp8(uint4 v, float* f){
  f[0]=__uint_as_float(v.x<<16); f[1]=__uint_as_float(v.x&0xffff0000u);
  f[2]=__uint_as_float(v.y<<16); f[3]=__uint_as_float(v.y&0xffff0000u);
  f[4]=__uint_as_float(v.z<<16); f[5]=__uint_as_float(v.z&0xffff0000u);
  f[6]=__uint_as_float(v.w<<16); f[7]=__uint_as_float(v.w&0xffff0000u);
}
__device__ __forceinline__ void unp4(uint2 v, float* f){
  f[0]=__uint_as_float(v.x<<16); f[1]=__uint_as_float(v.x&0xffff0000u);
  f[2]=__uint_as_float(v.y<<16); f[3]=__uint_as_float(v.y&0xffff0000u);
}

// tiled activation addressing: (R/128, C/32, 128, 32)
__device__ __forceinline__ size_t taddr(int r, int c, int C){
  return (size_t)(r >> 7) * ((size_t)C << 7) + (size_t)((c >> 5) << 12)
       + ((r & 127) << 5) + (c & 31);
}

// async global->LDS, 16B per lane; dest = wave-uniform base + lane*16
__device__ __forceinline__ void gload16(const void* g, void* l){
  __builtin_amdgcn_global_load_lds(
      (__attribute__((address_space(1))) void*)(g),
      (__attribute__((address_space(3))) void*)(l), 16, 0, 0);
}

// ------- merged prep: weights f32->bf16 (N,K) row-major | PE table | x f32->bf16 tiled ------
struct PrepArgs {
  const float* src[NSEG];
  int N[NSEG]; int K[NSEG]; int sn[NSEG]; int sk[NSEG]; unsigned off[NSEG];
};

__global__ __launch_bounds__(256) void prep_all(PrepArgs pa, u16* __restrict__ wb,
    float* __restrict__ pe, const float* __restrict__ x, u16* __restrict__ xb){
  int bid = blockIdx.x;
  if (bid < 256 * NSEG){
    int seg = bid >> 8;
    int tile = bid & 255;
    int N = pa.N[seg], K = pa.K[seg];
    int ntk = (K + 31) >> 5;
    int tiles = ((N + 31) >> 5) * ntk;
    if (tile >= tiles) return;
    int n0 = (tile / ntk) << 5, k0 = (tile % ntk) << 5;
    const float* src = pa.src[seg];
    long sn = pa.sn[seg], sk = pa.sk[seg];
    u16* dst = wb + pa.off[seg];
    int lk = threadIdx.x & 31, ln = threadIdx.x >> 5;
    #pragma unroll
    for (int i = 0; i < 4; ++i){
      int n = n0 + ln + i*8, k = k0 + lk;
      if (n < N && k < K)
        dst[(size_t)n*K + k] = f2b(src[(long)n*sn + (long)k*sk]);
    }
  } else if (bid < 256 * NSEG + 4096){
    int id = (bid - 256 * NSEG)*256 + threadIdx.x;   // 4096*256
    int s = id >> 8, i = id & 255;
    float div = expf((float)i * (-2.0f * 9.210340371976184f / 512.0f));
    float a = (float)s * div;
    pe[(size_t)s*512 + 2*i]   = sinf(a);
    pe[(size_t)s*512 + 2*i+1] = cosf(a);
  } else {
    int id = (bid - 256 * NSEG - 4096)*256 + threadIdx.x;  // 32768*64
    int r = id >> 6, c = id & 63;
    xb[taddr(r, c, 64)] = f2b(x[id]);
  }
}

// ========== 256x128 GEMM, K=512, BK=32, depth-3 stage-ahead-2 vmcnt(3), 2 blocks/CU ==========
// A tiled CA=512; W row-major (N, KTOT). flags: 1=relu 2=elu+1 4=+res 8=+pe 32=QKV
template<int KTOT>
__global__ __launch_bounds__(512, 4) void gemm9_k(
    const u16* __restrict__ A, const u16* __restrict__ W,
    const float* __restrict__ bias, const float* __restrict__ bias2,
    const float* __restrict__ bias3,
    u16* __restrict__ out, const u16* __restrict__ resb,
    const float* __restrict__ peb,
    int N, int nN, int flags)
{
  constexpr int KT = KTOT >> 5;    // ktiles of 32
  __shared__ u16 As[3][8192];      // 256 rows x 32 cols
  __shared__ u16 Bs[3][4096];      // 128 rows x 32 cols
  const int tid = threadIdx.x;
  const int wave = tid >> 6, lane = tid & 63;
  const int wm = wave >> 1, wn = wave & 1;     // 4m x 2n waves
  const int c0 = lane >> 4, fro = lane & 15;
  const int sr = tid >> 2, sp = tid & 3;       // staging row(128-group), phys chunk

  const int nwg = gridDim.x;
  const int lin = blockIdx.x;
  const int swz = (lin & 7) * (nwg >> 3) + (lin >> 3);
  const int mb = swz / nN, nb = swz - mb * nN;
  const int m0 = mb << 8, n0 = nb << 7;

  const f32x4 zf = {0.f,0.f,0.f,0.f};
  f32x4 acc[4][4];
  #pragma unroll
  for (int i=0;i<4;++i)
    #pragma unroll
    for (int j=0;j<4;++j) acc[i][j] = zf;

  auto SA = [&](int t, int half){
    int row = (half << 7) + sr;
    int lc = sp ^ ((row >> 1) & 3);
    int grow = m0 + row;
    size_t ga = ((size_t)(grow >> 7) << 16) + ((size_t)t << 12)
              + ((grow & 127) << 5) + (lc << 3);
    gload16(A + ga, &As[t % 3][(half << 12) + (wave << 9)]);
  };
  auto SB = [&](int t){
    int lc = sp ^ ((sr >> 1) & 3);
    gload16(W + (size_t)(n0 + sr) * KTOT + (t << 5) + (lc << 3),
            &Bs[t % 3][wave << 9]);
  };
  auto STG = [&](int s){ SA(s, 0); SA(s, 1); SB(s); };

  auto CMP = [&](int s){
    int b = s % 3;
    bhalf8 af[4], bf[4];
    #pragma unroll
    for (int mt = 0; mt < 4; ++mt){
      int row = (wm << 6) + (mt << 4) + fro;
      int phys = c0 ^ ((row >> 1) & 3);
      af[mt] = *(const bhalf8*)&As[b][row * 32 + (phys << 3)];
    }
    #pragma unroll
    for (int nt = 0; nt < 4; ++nt){
      int row = (wn << 6) + (nt << 4) + fro;
      int phys = c0 ^ ((row >> 1) & 3);
      bf[nt] = *(const bhalf8*)&Bs[b][row * 32 + (phys << 3)];
    }
    // swapped operands: per-thread 4 consecutive output cols
    #pragma unroll
    for (int mt = 0; mt < 4; ++mt)
      #pragma unroll
      for (int nt = 0; nt < 4; ++nt)
        acc[mt][nt] = __builtin_amdgcn_mfma_f32_16x16x32_bf16(bf[nt], af[mt], acc[mt][nt], 0, 0, 0);
  };

  STG(0);
  if (KT > 1) STG(1);
  #pragma unroll
  for (int s = 0; s < KT; ++s){
    if (s + 1 >= KT) asm volatile("s_waitcnt vmcnt(0)" ::: "memory");
    else             asm volatile("s_waitcnt vmcnt(3)" ::: "memory");
    __builtin_amdgcn_sched_barrier(0);
    __builtin_amdgcn_s_barrier();
    __builtin_amdgcn_sched_barrier(0);
    if (s + 2 < KT) STG(s + 2);
    CMP(s);
  }

  // ---- epilogue: row = m0+(wm<<6)+(mt<<4)+fro, cols 4-consecutive ----
  const int th = n0 >> 9;
  #pragma unroll
  for (int mt = 0; mt < 4; ++mt){
    const int row = m0 + (wm << 6) + (mt << 4) + fro;
    const size_t prow = (size_t)(row & (S_LEN - 1)) * 512;
    #pragma unroll
    for (int nt = 0; nt < 4; ++nt){
      const int col = n0 + (wn << 6) + (nt << 4) + (c0 << 2);
      float v0 = acc[mt][nt][0], v1 = acc[mt][nt][1], v2 = acc[mt][nt][2], v3 = acc[mt][nt][3];
      if (flags & 32){
        const float* bp = (th == 0) ? bias : ((th == 1) ? bias2 : bias3);
        if (bp){ float4 b4 = *(const float4*)&bp[col & 511]; v0+=b4.x; v1+=b4.y; v2+=b4.z; v3+=b4.w; }
      } else {
        if (bias){ float4 b4 = *(const float4*)&bias[col]; v0+=b4.x; v1+=b4.y; v2+=b4.z; v3+=b4.w; }
      }
      if (flags & 4){
        uint2 rv = *(const uint2*)(resb + taddr(row, col, N));
        float rf[4]; unp4(rv, rf);
        v0 += rf[0]; v1 += rf[1]; v2 += rf[2]; v3 += rf[3];
      }
      if (flags & 8){
        float4 p4 = *(const float4*)&peb[prow + col];
        v0 += p4.x; v1 += p4.y; v2 += p4.z; v3 += p4.w;
      }
      if (flags & 1){
        v0 = fmaxf(v0, 0.f); v1 = fmaxf(v1, 0.f); v2 = fmaxf(v2, 0.f); v3 = fmaxf(v3, 0.f);
      }
      if ((flags & 2) && (!(flags & 32) || th < 2)){
        v0 = (v0 > 0.f) ? (v0 + 1.f) : __expf(v0);
        v1 = (v1 > 0.f) ? (v1 + 1.f) : __expf(v1);
        v2 = (v2 > 0.f) ? (v2 + 1.f) : __expf(v2);
        v3 = (v3 > 0.f) ? (v3 + 1.f) : __expf(v3);
      }
      uint2 pk; pk.x = cvtpk(v0, v1); pk.y = cvtpk(v2, v3);
      *(uint2*)(out + taddr(row, col, N)) = pk;
    }
  }
}

// ---------------- 128x(64*NWT) GEMM. 1-tap: 3-buf stage-ahead-2 vmcnt(4).
// 3-tap non-fused: stage-ahead-2, DA=2, DB=3, vmcnt(2) -> 5 blocks/CU.
// 3-tap fused (KS2>0): stage-ahead-3, DA=4, DB=4, vmcnt(2) -> 3 blocks/CU.
// NWT=1: 4m-waves of 32x64 (acc[2][4]); NWT=2: 2m x 2n waves of 64x64 (acc[4][4]).
template<int NTAPS, int KS1, int KS2, int NWT>
__global__ __launch_bounds__(256) void gemm_k(
    const u16* __restrict__ A, const u16* __restrict__ W,
    const u16* __restrict__ A2, const u16* __restrict__ W2,
    const float* __restrict__ bias, const float* __restrict__ bias2,
    const float* __restrict__ bias3,
    u16* __restrict__ out, const u16* __restrict__ resb,
    const float* __restrict__ peb, const float* __restrict__ den,
    int N, int CA, int CA2, int dil, int nN, int wbstride, int flags)
{
  constexpr bool MT   = (NTAPS == 3);
  constexpr bool FS   = (MT && KS2 > 0);   // fused ds phase
  constexpr int HALO  = MT ? 8 : 0;
  constexpr int AR    = MT ? 144 : 128;
  constexpr int DA    = MT ? (FS ? 4 : 2) : 3;
  constexpr int DB    = MT ? (FS ? 4 : 3) : 3;
  constexpr int AH    = MT ? (FS ? 3 : 2) : 2;   // stage-ahead depth
  constexpr int K     = KS1 << 5;
  constexpr int K2    = KS2 << 5;
  constexpr int TOTAL = MT ? (3*KS1 + KS2) : (KS1 + KS2);
  constexpr int BC    = NWT << 6;          // B rows (output cols per block)
  constexpr int MFR   = (NWT == 2) ? 4 : 2; // m fragments per wave
  __shared__ u16 As[DA][AR*32];
  __shared__ u16 Bs[DB][BC*32];
  const int tid = threadIdx.x;
  const int wave = tid >> 6, lane = tid & 63;
  const int wm = (NWT == 2) ? (wave >> 1) : wave;
  const int wn = (NWT == 2) ? (wave & 1) : 0;
  const int wrow0 = wm * (MFR << 4);
  const int wcol0 = wn << 6;

  const int nwg = gridDim.x;
  const int lin = blockIdx.x;
  const int swz = (lin & 7) * (nwg >> 3) + (lin >> 3);
  const int mb = swz / nN, nb = swz - mb * nN;
  const int m0 = mb << 7, n0 = nb * BC;
  const bool bnd = (m0 & (S_LEN - 1)) == 0;

  const u16* Ae = (flags & 16) ? (A + (((size_t)(n0 & 511) >> 5) << 12)) : A;

  const int lr4 = lane >> 2, lc4 = lane & 3;
  const int c0 = lane >> 4, fro = lane & 15;

  const f32x4 zf = {0.f, 0.f, 0.f, 0.f};
  const bhalf8 zb = {0,0,0,0,0,0,0,0};
  f32x4 acc[MFR][4];
  #pragma unroll
  for (int i=0;i<MFR;++i)
    #pragma unroll
    for (int j=0;j<4;++j) acc[i][j] = zf;

  const u16* Wb = W + (size_t)(m0 >> 12) * (size_t)wbstride;
  const size_t abase  = (size_t)mb * ((size_t)CA  << 7);
  const size_t abase2 = (size_t)mb * ((size_t)CA2 << 7);

  auto STAGE_A = [&](int kb, int ab){
    const size_t tb = abase + ((size_t)kb << 12);
    #pragma unroll
    for (int half = 0; half < 2; ++half){
      int mrow = (wave << 5) + (half << 4) + lr4;
      int i = mrow + HALO;
      int cg = lc4 ^ ((i >> 1) & 3);
      gload16(Ae + tb + mrow*32 + (cg << 3), &As[ab][(HALO + (wave << 5) + (half << 4)) * 32]);
    }
    if (MT && wave == 0 && lane < 32){
      int j = lr4;
      int cg = lc4 ^ ((j >> 1) & 3);
      size_t hb_ = (mb ? abase - ((size_t)CA << 7) : abase) + ((size_t)kb << 12) + (120 + j)*32;
      gload16(Ae + hb_ + (cg << 3), &As[ab][0]);
    }
  };
  auto STAGE_A2 = [&](int t2, int ab){
    const size_t tb = abase2 + ((size_t)t2 << 12);
    #pragma unroll
    for (int half = 0; half < 2; ++half){
      int mrow = (wave << 5) + (half << 4) + lr4;
      int i = mrow + HALO;
      int cg = lc4 ^ ((i >> 1) & 3);
      gload16(A2 + tb + mrow*32 + (cg << 3), &As[ab][(HALO + (wave << 5) + (half << 4)) * 32]);
    }
  };
  auto STAGE_B = [&](const u16* Wt, size_t kstride, int kb, int bb){
    #pragma unroll
    for (int h = 0; h < NWT; ++h){
      int i = wave * (NWT << 4) + (h << 4) + lr4;
      int cg = lc4 ^ ((i >> 1) & 3);
      gload16(Wt + (size_t)(n0 + i) * kstride + (kb << 5) + (cg << 3),
              &Bs[bb][(wave * (NWT << 4) + (h << 4)) * 32]);
    }
  };
  auto DOMM = [&](int ab, int bb, int sh, bool mask){
    bhalf8 af[MFR], bf[4];
    #pragma unroll
    for (int mt = 0; mt < MFR; ++mt){
      int r8 = wrow0 + (mt << 4) + fro + HALO + sh;
      af[mt] = *(const bhalf8*)&As[ab][r8 * 32 + ((c0 ^ ((r8 >> 1) & 3)) << 3)];
    }
    if (MT && mask && bnd && wm == 0 && fro + sh < 0) af[0] = zb;
    #pragma unroll
    for (int nt = 0; nt < 4; ++nt){
      int rB = wcol0 + (nt << 4) + fro;
      bf[nt] = *(const bhalf8*)&Bs[bb][rB * 32 + ((c0 ^ ((rB >> 1) & 3)) << 3)];
    }
    #pragma unroll
    for (int mt = 0; mt < MFR; ++mt)
      #pragma unroll
      for (int nt = 0; nt < 4; ++nt)
        acc[mt][nt] = __builtin_amdgcn_mfma_f32_16x16x32_bf16(bf[nt], af[mt], acc[mt][nt], 0, 0, 0);
  };

  if constexpr (!MT){
    auto STG = [&](int s){
      int b = s % 3;
      if (s < KS1){ STAGE_A(s, b); STAGE_B(Wb, (size_t)K, s, b); }
      else if (KS2 > 0){ STAGE_A2(s - KS1, b); STAGE_B(W2, (size_t)K2, s - KS1, b); }
    };
    STG(0);
    if constexpr (TOTAL > 1) STG(1);
    #pragma unroll
    for (int s = 0; s < TOTAL; ++s){
      if (s + 1 >= TOTAL) asm volatile("s_waitcnt vmcnt(0)" ::: "memory");
      else                asm volatile("s_waitcnt vmcnt(4)" ::: "memory");
      __builtin_amdgcn_sched_barrier(0);
      __builtin_amdgcn_s_barrier();
      __builtin_amdgcn_sched_barrier(0);
      if (s + 2 < TOTAL) STG(s + 2);
      DOMM(s % 3, s % 3, 0, false);
    }
  } else {
    auto STG = [&](int s){
      if (s < 3*KS1){
        int kb = s / 3, tap = s % 3;
        if (tap == 0) STAGE_A(kb, kb % DA);
        STAGE_B(Wb + (size_t)tap * N * K, (size_t)K, kb, s % DB);
      } else if (KS2 > 0){
        int t2 = s - 3*KS1;
        STAGE_A2(t2, (KS1 + t2) % DA);
        STAGE_B(W2, (size_t)K2, t2, s % DB);
      }
    };
    STG(0);
    if constexpr (TOTAL > 1) STG(1);
    if constexpr (AH >= 3 && TOTAL > 2) STG(2);
    #pragma unroll
    for (int s = 0; s < TOTAL; ++s){
      if (s + 1 >= TOTAL)      asm volatile("s_waitcnt vmcnt(0)" ::: "memory");
      else if (s + 2 >= TOTAL) asm volatile("s_waitcnt vmcnt(1)" ::: "memory");
      else                     asm volatile("s_waitcnt vmcnt(2)" ::: "memory");
      __builtin_amdgcn_sched_barrier(0);
      __builtin_amdgcn_s_barrier();
      __builtin_amdgcn_sched_barrier(0);
      if (s + AH < TOTAL) STG(s + AH);
      if (s < 3*KS1) DOMM((s/3) % DA, s % DB, ((s%3) - 2) * dil, true);
      else           DOMM((KS1 + (s - 3*KS1)) % DA, s % DB, 0, false);
    }
  }

  const int mb_l = wrow0 + fro;
  const int cb_l = wcol0 + (c0 << 2);
  const int th = n0 >> 9;
  #pragma unroll
  for (int mt = 0; mt < MFR; ++mt){
    const int row = m0 + mb_l + (mt << 4);
    const size_t prow = (size_t)(row & (S_LEN - 1)) * 512;
    #pragma unroll
    for (int nt = 0; nt < 4; ++nt){
      const int col = n0 + cb_l + (nt << 4);
      float v0 = acc[mt][nt][0], v1 = acc[mt][nt][1], v2 = acc[mt][nt][2], v3 = acc[mt][nt][3];
      if (flags & 32){
        const float* bp = (th == 0) ? bias : ((th == 1) ? bias2 : bias3);
        if (bp){ float4 b4 = *(const float4*)&bp[col & 511]; v0+=b4.x; v1+=b4.y; v2+=b4.z; v3+=b4.w; }
      } else {
        if (bias) { float4 b4 = *(const float4*)&bias[col];  v0+=b4.x; v1+=b4.y; v2+=b4.z; v3+=b4.w; }
        if (bias2){ float4 b4 = *(const float4*)&bias2[col]; v0+=b4.x; v1+=b4.y; v2+=b4.z; v3+=b4.w; }
      }
      if (flags & 4){
        uint2 rv = *(const uint2*)(resb + taddr(row, col, N));
        float rf[4]; unp4(rv, rf);
        v0 += rf[0]; v1 += rf[1]; v2 += rf[2]; v3 += rf[3];
      }
      if (flags & 8){
        float4 p4 = *(const float4*)&peb[prow + col];
        v0 += p4.x; v1 += p4.y; v2 += p4.z; v3 += p4.w;
      }
      if (flags & 16){
        float d = fmaxf(den[((size_t)row << 3) + (col >> 6)], 1e-6f);
        float rd = 1.0f / d;
        v0 *= rd; v1 *= rd; v2 *= rd; v3 *= rd;
      }
      if (flags & 1){
        v0 = fmaxf(v0, 0.f); v1 = fmaxf(v1, 0.f); v2 = fmaxf(v2, 0.f); v3 = fmaxf(v3, 0.f);
      }
      if ((flags & 2) && (!(flags & 32) || th < 2)){
        v0 = (v0 > 0.f) ? (v0 + 1.f) : __expf(v0);
        v1 = (v1 > 0.f) ? (v1 + 1.f) : __expf(v1);
        v2 = (v2 > 0.f) ? (v2 + 1.f) : __expf(v2);
        v3 = (v3 > 0.f) ? (v3 + 1.f) : __expf(v3);
      }
      uint2 pk; pk.x = cvtpk(v0, v1); pk.y = cvtpk(v2, v3);
      *(uint2*)(out + taddr(row, col, N)) = pk;
    }
  }
}

// ---------------- linear attention: partial kv = sum_n kf (outer) v, ksum ----------------
// double-buffered LDS, issue-early/write-late (T14): 1 barrier per 16-row tile
__global__ __launch_bounds__(256) void kv_partial(
    const u16* __restrict__ qkv,
    float* __restrict__ kvp, float* __restrict__ ksp)
{
  const int bh = blockIdx.x;
  const int b = bh >> 3, h = bh & 7;
  const int ch = blockIdx.y;
  const int t = threadIdx.x;
  __shared__ u16 kfs[2][16][64];
  __shared__ u16 vs[2][16][64];
  float acc[4][4] = {{0.f}};
  float ks[4] = {0.f,0.f,0.f,0.f};
  const int d0 = (t >> 4) << 2;
  const int c0 = (t & 15) << 2;
  const int lr = t >> 4, lc = (t & 15) << 2;
  const int rowbase = (b << 12) + (ch << 9);
  const int ck = 512 + (h << 6) + lc;
  const int cv = 1024 + (h << 6) + lc;

  uint2 rk = *(const uint2*)(qkv + taddr(rowbase + lr, ck, 1536));
  uint2 rv = *(const uint2*)(qkv + taddr(rowbase + lr, cv, 1536));
  *(uint2*)&kfs[0][lr][lc] = rk;
  *(uint2*)&vs[0][lr][lc]  = rv;
  __syncthreads();
  int cur = 0;
  for (int g = 0; g < 32; ++g){
    if (g + 1 < 32){
      int r = rowbase + ((g + 1) << 4) + lr;
      rk = *(const uint2*)(qkv + taddr(r, ck, 1536));
      rv = *(const uint2*)(qkv + taddr(r, cv, 1536));
    }
    #pragma unroll
    for (int i = 0; i < 16; ++i){
      float kv4[4], vv4[4];
      unp4(*(const uint2*)&kfs[cur][i][d0], kv4);
      unp4(*(const uint2*)&vs[cur][i][c0], vv4);
      #pragma unroll
      for (int j=0;j<4;++j)
        #pragma unroll
        for (int k2=0;k2<4;++k2) acc[j][k2] += kv4[j]*vv4[k2];
      if ((t & 15) == 0){
        #pragma unroll
        for (int j=0;j<4;++j) ks[j] += kv4[j];
      }
    }
    if (g + 1 < 32){
      *(uint2*)&kfs[cur ^ 1][lr][lc] = rk;
      *(uint2*)&vs[cur ^ 1][lr][lc]  = rv;
    }
    __syncthreads();
    cur ^= 1;
  }
  float* dst = kvp + ((size_t)(bh << 3) + ch) * 4096;
  #pragma unroll
  for (int j=0;j<4;++j)
    #pragma unroll
    for (int k2=0;k2<4;++k2) dst[(d0+j)*64 + (c0+k2)] = acc[j][k2];
  if ((t & 15) == 0){
    float* kd = ksp + ((size_t)(bh << 3) + ch) * 64;
    #pragma unroll
    for (int j=0;j<4;++j) kd[d0+j] = ks[j];
  }
}

__global__ __launch_bounds__(256) void kvred_k(
    const float* __restrict__ kvp, const float* __restrict__ ksp,
    float* __restrict__ kvf, float* __restrict__ ksf)
{
  int bh = blockIdx.x, t = threadIdx.x;
  for (int e = t; e < 4096; e += 256){
    float s = 0.f;
    #pragma unroll
    for (int ch = 0; ch < 8; ++ch) s += kvp[((size_t)(bh<<3)+ch)*4096 + e];
    kvf[(size_t)bh*4096 + e] = s;
  }
  if (t < 64){
    float s = 0.f;
    #pragma unroll
    for (int ch = 0; ch < 8; ++ch) s += ksp[((size_t)(bh<<3)+ch)*64 + t];
    ksf[bh*64 + t] = s;
  }
}

// merged: blocks [0,1024) compute den; blocks [1024,3072) pack wbd
__global__ __launch_bounds__(256) void denpack_k(const u16* __restrict__ qkv,
    const float* __restrict__ ksf, float* __restrict__ den,
    const float* __restrict__ kvf, u16* __restrict__ wbd)
{
  int bid = blockIdx.x;
  if (bid < 1024){
    int id = bid*256 + threadIdx.x;
    int r = id >> 3, h = id & 7;
    int b = r >> 12;
    const float* ks = ksf + ((b<<3)+h)*64;
    float s = 0.f;
    for (int d = 0; d < 64; d += 8){
      uint4 vq = *(const uint4*)(qkv + taddr(r, (h << 6) + d, 1536));
      float f[8]; unp8(vq, f);
      #pragma unroll
      for (int j=0;j<8;++j) s += f[j]*ks[d+j];
    }
    den[id] = s;
  } else {
    int id = (bid - 1024)*256 + threadIdx.x;   // 8*512*128
    int b = id >> 16;
    int n = (id >> 7) & 511, j = id & 127;
    float v = 0.f;
    if ((j >> 6) == ((n >> 6) & 1))
      v = kvf[((size_t)((b<<3)+(n>>6)))*4096 + (j & 63)*64 + (n & 63)];
    wbd[id] = f2b(v);
  }
}

__global__ __launch_bounds__(256) void ln_k(const u16* __restrict__ in,
    const float* __restrict__ g, const float* __restrict__ beta, u16* __restrict__ out)
{
  int wave = threadIdx.x >> 6, lane = threadIdx.x & 63;
  int row = blockIdx.x*4 + wave;
  size_t ad = taddr(row, lane*8, 512);
  uint4 pv = *(const uint4*)(in + ad);
  float f[8]; unp8(pv, f);
  float s = 0.f, ss = 0.f;
  #pragma unroll
  for (int i=0;i<8;++i){ s += f[i]; ss += f[i]*f[i]; }
  for (int m=1;m<64;m<<=1){ s += __shfl_xor(s,m); ss += __shfl_xor(ss,m); }
  float mean = s * (1.f/512.f);
  float var = ss * (1.f/512.f) - mean*mean;
  float rstd = rsqrtf(fmaxf(var, 0.f) + 1e-5f);
  u16 o[8];
  #pragma unroll
  for (int i=0;i<8;++i){
    int c = lane*8 + i;
    o[i] = f2b((f[i]-mean)*rstd*g[c] + beta[c]);
  }
  *(uint4*)(out + ad) = *(uint4*)o;
}

// ------- fused LN + mean-pool + dot W_out
__global__ __launch_bounds__(256) void pool1_k(const u16* __restrict__ hb,
    const float* __restrict__ wout, const float* __restrict__ g,
    const float* __restrict__ beta, float* __restrict__ part)
{
  int b = blockIdx.x >> 6, ch = blockIdx.x & 63;
  int t = threadIdx.x;
  __shared__ float ws[512];
  __shared__ float red[256];
  __shared__ float S2[2];
  float a0 = 0.f, a1 = 0.f;
  for (int i = t; i < 512; i += 256){
    float w = wout[i];
    float gw = w * g[i];
    ws[i] = gw;
    a0 += gw;
    a1 += w * beta[i];
  }
  red[t] = a0; __syncthreads();
  for (int k2=128;k2;k2>>=1){ if (t<k2) red[t]+=red[t+k2]; __syncthreads(); }
  if (!t) S2[0] = red[0];
  __syncthreads();
  red[t] = a1; __syncthreads();
  for (int k2=128;k2;k2>>=1){ if (t<k2) red[t]+=red[t+k2]; __syncthreads(); }
  if (!t) S2[1] = red[0];
  __syncthreads();
  const float Sgw = S2[0], Sbw = S2[1];

  int r = (b << 12) + (ch << 6) + (t >> 2);
  int c0 = (t & 3) << 7;
  float sd = 0.f, s1 = 0.f, s2 = 0.f;
  for (int i = 0; i < 128; i += 8){
    uint4 v = *(const uint4*)(hb + taddr(r, c0 + i, 512));
    float f[8]; unp8(v, f);
    #pragma unroll
    for (int j=0;j<8;++j){ float x = f[j]; sd += x*ws[c0+i+j]; s1 += x; s2 += x*x; }
  }
  sd += __shfl_xor(sd,1); s1 += __shfl_xor(s1,1); s2 += __shfl_xor(s2,1);
  sd += __shfl_xor(sd,2); s1 += __shfl_xor(s1,2); s2 += __shfl_xor(s2,2);
  float mean = s1 * (1.f/512.f);
  float var  = s2 * (1.f/512.f) - mean*mean;
  float rstd = rsqrtf(fmaxf(var, 0.f) + 1e-5f);
  float rowv = rstd * (sd - mean * Sgw) + Sbw;
  red[t] = ((t & 3) == 0) ? rowv : 0.f;
  __syncthreads();
  for (int k2=128;k2;k2>>=1){ if (t<k2) red[t]+=red[t+k2]; __syncthreads(); }
  if (!t) part[blockIdx.x] = red[0];
}

__global__ __launch_bounds__(64) void pool2_k(const float* __restrict__ part,
    const float* __restrict__ bout, float* __restrict__ out)
{
  int b = blockIdx.x, t = threadIdx.x;
  float s = part[(b << 6) + t];
  for (int m=1;m<64;m<<=1) s += __shfl_xor(s,m);
  if (!t) out[b] = s * (1.f/4096.f) + bout[0];
}

// =========================================================================
extern "C" void kernel_launch(void* const* d_in, const int* in_sizes, int n_in,
                              void* d_out, int out_size, void* d_ws, size_t ws_size,
                              hipStream_t stream)
{
  (void)in_sizes; (void)n_in; (void)out_size; (void)ws_size;
  const float* x    = (const float*)d_in[0];
  const float* W_in = (const float*)d_in[1];
  const float* b_in = (const float*)d_in[2];
  const float* c1w0 = (const float*)d_in[3];
  const float* c1b0 = (const float*)d_in[4];
  const float* c2w0 = (const float*)d_in[5];
  const float* c2b0 = (const float*)d_in[6];
  const float* dsw0 = (const float*)d_in[7];
  const float* dsb0 = (const float*)d_in[8];
  const float* c1w1 = (const float*)d_in[9];
  const float* c1b1 = (const float*)d_in[10];
  const float* c2w1 = (const float*)d_in[11];
  const float* c2b1 = (const float*)d_in[12];
  const float* c1w2 = (const float*)d_in[13];
  const float* c1b2 = (const float*)d_in[14];
  const float* c2w2 = (const float*)d_in[15];
  const float* c2b2 = (const float*)d_in[16];
  const float* dsw2 = (const float*)d_in[17];
  const float* dsb2 = (const float*)d_in[18];
  const float* W_tcn= (const float*)d_in[19];
  const float* b_tcn= (const float*)d_in[20];
  const float* Wq   = (const float*)d_in[21];
  const float* Wk   = (const float*)d_in[22];
  const float* Wv   = (const float*)d_in[23];
  const float* Wo   = (const float*)d_in[24];
  const float* bq   = (const float*)d_in[25];
  const float* bk   = (const float*)d_in[26];
  const float* bv   = (const float*)d_in[27];
  const float* bo   = (const float*)d_in[28];
  const float* lnb  = (const float*)d_in[29];
  const float* lng  = (const float*)d_in[30];
  const float* W_out= (const float*)d_in[31];
  const float* b_out= (const float*)d_in[32];

  char* base = (char*)d_ws;
  size_t off = 0;
  auto alloc = [&](size_t bytes) -> void* {
    void* p = base + off;
    off += (bytes + 255) & ~(size_t)255;
    return p;
  };
  u16* WB   = (u16*)alloc(4816896ull*2);
  u16* wbd  = (u16*)alloc(8ull*512*128*2);
  float* peb= (float*)alloc(4096ull*512*4);
  float* den= (float*)alloc(32768ull*8*4);
  float* kvp= (float*)alloc(512ull*4096*4);
  float* ksp= (float*)alloc(512ull*64*4);
  float* kvf= (float*)alloc(64ull*4096*4);
  float* ksf= (float*)alloc(64ull*64*4);
  float* part=(float*)alloc(512*4);
  u16* hb   = (u16*)alloc(32768ull*512*2);
  char* qkvR= (char*)alloc(32768ull*1536*2);
  u16* atto = (u16*)alloc(32768ull*512*2);

  u16* qkvb = (u16*)qkvR;
  u16* xb   = (u16*)(qkvR);
  u16* t1b  = (u16*)(qkvR + 4194304);
  u16* t2b  = (u16*)(qkvR + 20971520);
  u16* t3b  = (u16*)(qkvR + 37748736);
  u16* o1b  = atto;

  unsigned wo_ = 0;
  auto wseg = [&](unsigned e){ unsigned o = wo_; wo_ += e; return o; };
  unsigned oWin  = wseg(512*64);
  unsigned oC1w0 = wseg(3*256*512);
  unsigned oC2w0 = wseg(3*256*256);
  unsigned oDs0  = wseg(256*512);
  unsigned oC1w1 = wseg(3*256*256);
  unsigned oC2w1 = wseg(3*256*256);
  unsigned oC1w2 = wseg(3*512*256);
  unsigned oC2w2 = wseg(3*512*512);
  unsigned oDs2  = wseg(512*256);
  unsigned oWtcn = wseg(512*512);
  unsigned oQKV  = wseg(2*1536*512);
  unsigned oWo   = wseg(2*512*512);

  PrepArgs pa;
  int si = 0;
  auto seg = [&](const float* s, int N, int K, int sn, int sk, unsigned o){
    pa.src[si]=s; pa.N[si]=N; pa.K[si]=K; pa.sn[si]=sn; pa.sk[si]=sk; pa.off[si]=o; ++si;
  };
  seg(W_in, 512, 64, 1, 512, oWin);
  for (int t=0;t<3;++t) seg(c1w0 + t, 256, 512, 1536, 3, oC1w0 + t*131072);
  for (int t=0;t<3;++t) seg(c2w0 + t, 256, 256,  768, 3, oC2w0 + t*65536);
  seg(dsw0, 256, 512, 512, 1, oDs0);
  for (int t=0;t<3;++t) seg(c1w1 + t, 256, 256,  768, 3, oC1w1 + t*65536);
  for (int t=0;t<3;++t) seg(c2w1 + t, 256, 256,  768, 3, oC2w1 + t*65536);
  for (int t=0;t<3;++t) seg(c1w2 + t, 512, 256,  768, 3, oC1w2 + t*131072);
  for (int t=0;t<3;++t) seg(c2w2 + t, 512, 512, 1536, 3, oC2w2 + t*262144);
  seg(dsw2, 512, 256, 256, 1, oDs2);
  seg(W_tcn, 512, 512, 1, 512, oWtcn);
  for (int l=0;l<2;++l){
    seg(Wq + l*262144, 512, 512, 1, 512, oQKV + l*786432 + 0);
    seg(Wk + l*262144, 512, 512, 1, 512, oQKV + l*786432 + 262144);
    seg(Wv + l*262144, 512, 512, 1, 512, oQKV + l*786432 + 524288);
  }
  for (int l=0;l<2;++l) seg(Wo + l*262144, 512, 512, 1, 512, oWo + l*262144);

  // merged prep: weights | PE | x-convert
  prep_all<<<dim3(256*NSEG + 4096 + 8192), 256, 0, stream>>>(pa, WB, peb, x, xb);

  const int RELU=1, ELU1=2, RES=4, PE=8, DIV=16, QKV=32;
  // 3-tap convs: 128x64 tiles (NWT=1); 1-tap small-K: 128x128 (NWT=2)
  auto gemm = [&](const u16* A, const u16* W, const u16* A2, const u16* W2,
                  const float* b1, const float* b2, const float* b3,
                  u16* out, const u16* resb,
                  int K, int K2, int N, int CA, int CA2, int ntaps,
                  int dil, int wbs, int flags){
    if (ntaps == 3){
      int nN = N >> 6;
      dim3 grid(256 * nN);
      if (K == 512 && K2 == 0)
        gemm_k<3,16,0,1><<<grid, 256, 0, stream>>>(A, W, A2, W2, b1, b2, b3, out, resb,
                                                   peb, den, N, CA, CA2, dil, nN, wbs, flags);
      else if (K == 256 && K2 == 512)
        gemm_k<3,8,16,1><<<grid, 256, 0, stream>>>(A, W, A2, W2, b1, b2, b3, out, resb,
                                                   peb, den, N, CA, CA2, dil, nN, wbs, flags);
      else if (K == 256 && K2 == 0)
        gemm_k<3,8,0,1><<<grid, 256, 0, stream>>>(A, W, A2, W2, b1, b2, b3, out, resb,
                                                  peb, den, N, CA, CA2, dil, nN, wbs, flags);
      else
        gemm_k<3,16,8,1><<<grid, 256, 0, stream>>>(A, W, A2, W2, b1, b2, b3, out, resb,
                                                   peb, den, N, CA, CA2, dil, nN, wbs, flags);
    } else {
      int nN = N >> 7;
      dim3 grid(256 * nN);
      if (K == 64)
        gemm_k<1,2,0,2><<<grid, 256, 0, stream>>>(A, W, A2, W2, b1, b2, b3, out, resb,
                                                  peb, den, N, CA, CA2, dil, nN, wbs, flags);
      else
        gemm_k<1,4,0,2><<<grid, 256, 0, stream>>>(A, W, A2, W2, b1, b2, b3, out, resb,
                                                  peb, den, N, CA, CA2, dil, nN, wbs, flags);
    }
  };
  // 256x128 2-blocks/CU path for K=512 1-tap GEMMs (A tiled CA=512, W row-major K=512)
  auto gemm9 = [&](const u16* A, const u16* W, const float* b1, const float* b2,
                   const float* b3, u16* out, const u16* resb, int N, int flags){
    int nN = N >> 7;
    gemm9_k<512><<<dim3(128 * nN), 512, 0, stream>>>(A, W, b1, b2, b3, out, resb,
                                                     peb, N, nN, flags);
  };

  // input projection: h = x @ W_in + b_in
  gemm(xb, WB + oWin, nullptr, nullptr, b_in, nullptr, nullptr, hb, nullptr,
       64, 0, 512, 64, 0, 1, 1, 0, 0);
  // TCN block 0 (dil=1, 512->256, fused ds)
  gemm(hb,  WB + oC1w0, nullptr, nullptr, c1b0, nullptr, nullptr, o1b, nullptr,
       512, 0, 256, 512, 0, 3, 1, 0, RELU);
  gemm(o1b, WB + oC2w0, hb, WB + oDs0, c2b0, dsb0, nullptr, t1b, nullptr,
       256, 512, 256, 256, 512, 3, 1, 0, RELU);
  // TCN block 1 (dil=2, 256->256, identity residual)
  gemm(t1b, WB + oC1w1, nullptr, nullptr, c1b1, nullptr, nullptr, o1b, nullptr,
       256, 0, 256, 256, 0, 3, 2, 0, RELU);
  gemm(o1b, WB + oC2w1, nullptr, nullptr, c2b1, nullptr, nullptr, t2b, t1b,
       256, 0, 256, 256, 0, 3, 2, 0, RELU|RES);
  // TCN block 2 (dil=4, 256->512, fused ds)
  gemm(t2b, WB + oC1w2, nullptr, nullptr, c1b2, nullptr, nullptr, o1b, nullptr,
       256, 0, 512, 256, 0, 3, 4, 0, RELU);
  gemm(o1b, WB + oC2w2, t2b, WB + oDs2, c2b2, dsb2, nullptr, t3b, nullptr,
       512, 256, 512, 512, 256, 3, 4, 0, RELU);
  // h = h + t3 @ W_tcn + b_tcn + pe   (256x128 path, in-place residual)
  gemm9(t3b, WB + oWtcn, b_tcn, nullptr, nullptr, hb, hb, 512, RES|PE);

  for (int l = 0; l < 2; ++l){
    // fused QKV: qkvb = [elu(q)+1 | elu(k)+1 | v]  (N=1536)
    gemm9(hb, WB + oQKV + l*786432, bq + l*512, bk + l*512, bv + l*512,
          qkvb, nullptr, 1536, ELU1|QKV);
    kv_partial<<<dim3(64, 8), 256, 0, stream>>>(qkvb, kvp, ksp);
    kvred_k<<<64, 256, 0, stream>>>(kvp, ksp, kvf, ksf);
    denpack_k<<<3072, 256, 0, stream>>>(qkvb, ksf, den, kvf, wbd);
    // atto = (qf @ kv) / den   (block-diag, K=128 window per n-tile)
    gemm(qkvb, wbd, nullptr, nullptr, nullptr, nullptr, nullptr, atto, nullptr,
         128, 0, 512, 1536, 0, 1, 1, 512*128, DIV);
    // h = h + atto @ Wo + bo  (256x128 path, in-place residual)
    gemm9(atto, WB + oWo + l*262144, bo + l*512, nullptr, nullptr, hb, hb, 512, RES);
    if (l == 0)
      ln_k<<<8192, 256, 0, stream>>>(hb, lng, lnb, hb);
  }

  pool1_k<<<512, 256, 0, stream>>>(hb, W_out, lng + 512, lnb + 512, part);
  pool2_k<<<8, 64, 0, stream>>>(part, b_out, (float*)d_out);
}

// Round 17
// 675.682 us; speedup vs baseline: 1.0448x; 1.0448x over previous
//
#include <hip/hip_runtime.h>

typedef unsigned short u16;
typedef unsigned int u32;
typedef short bhalf8 __attribute__((ext_vector_type(8)));
typedef float f32x4 __attribute__((ext_vector_type(4)));

#define S_LEN 4096
#define NSEG 30

__device__ __forceinline__ float b2f(u16 h){ return __uint_as_float(((u32)h) << 16); }
__device__ __forceinline__ u16 f2b(float f){
  u32 u = __float_as_uint(f);
  return (u16)((u + 0x7FFFu + ((u >> 16) & 1u)) >> 16);
}
__device__ __forceinline__ u32 cvtpk(float a, float b){
  u32 r; asm("v_cvt_pk_bf16_f32 %0, %1, %2" : "=v"(r) : "v"(a), "v"(b)); return r;
}
__device__ __forceinline__ void unp8(uint4 v, float* f){
  f[0]=__uint_as_float(v.x<<16); f[1]=__uint_as_float(v.x&0xffff0000u);
  f[2]=__uint_as_float(v.y<<16); f[3]=__uint_as_float(v.y&0xffff0000u);
  f[4]=__uint_as_float(v.z<<16); f[5]=__uint_as_float(v.z&0xffff0000u);
  f[6]=__uint_as_float(v.w<<16); f[7]=__uint_as_float(v.w&0xffff0000u);
}
__device__ __forceinline__ void unp4(uint2 v, float* f){
  f[0]=__uint_as_float(v.x<<16); f[1]=__uint_as_float(v.x&0xffff0000u);
  f[2]=__uint_as_float(v.y<<16); f[3]=__uint_as_float(v.y&0xffff0000u);
}

// tiled activation addressing: (R/128, C/32, 128, 32)
__device__ __forceinline__ size_t taddr(int r, int c, int C){
  return (size_t)(r >> 7) * ((size_t)C << 7) + (size_t)((c >> 5) << 12)
       + ((r & 127) << 5) + (c & 31);
}

// async global->LDS, 16B per lane; dest = wave-uniform base + lane*16
__device__ __forceinline__ void gload16(const void* g, void* l){
  __builtin_amdgcn_global_load_lds(
      (__attribute__((address_space(1))) void*)(g),
      (__attribute__((address_space(3))) void*)(l), 16, 0, 0);
}

// ------- merged prep: weights f32->bf16 (N,K) row-major | PE table | x f32->bf16 tiled ------
struct PrepArgs {
  const float* src[NSEG];
  int N[NSEG]; int K[NSEG]; int sn[NSEG]; int sk[NSEG]; unsigned off[NSEG];
};

__global__ __launch_bounds__(256) void prep_all(PrepArgs pa, u16* __restrict__ wb,
    float* __restrict__ pe, const float* __restrict__ x, u16* __restrict__ xb){
  int bid = blockIdx.x;
  if (bid < 256 * NSEG){
    int seg = bid >> 8;
    int tile = bid & 255;
    int N = pa.N[seg], K = pa.K[seg];
    int ntk = (K + 31) >> 5;
    int tiles = ((N + 31) >> 5) * ntk;
    if (tile >= tiles) return;
    int n0 = (tile / ntk) << 5, k0 = (tile % ntk) << 5;
    const float* src = pa.src[seg];
    long sn = pa.sn[seg], sk = pa.sk[seg];
    u16* dst = wb + pa.off[seg];
    int lk = threadIdx.x & 31, ln = threadIdx.x >> 5;
    #pragma unroll
    for (int i = 0; i < 4; ++i){
      int n = n0 + ln + i*8, k = k0 + lk;
      if (n < N && k < K)
        dst[(size_t)n*K + k] = f2b(src[(long)n*sn + (long)k*sk]);
    }
  } else if (bid < 256 * NSEG + 4096){
    int id = (bid - 256 * NSEG)*256 + threadIdx.x;   // 4096*256
    int s = id >> 8, i = id & 255;
    float div = expf((float)i * (-2.0f * 9.210340371976184f / 512.0f));
    float a = (float)s * div;
    pe[(size_t)s*512 + 2*i]   = sinf(a);
    pe[(size_t)s*512 + 2*i+1] = cosf(a);
  } else {
    int id = (bid - 256 * NSEG - 4096)*256 + threadIdx.x;  // 32768*64
    int r = id >> 6, c = id & 63;
    xb[taddr(r, c, 64)] = f2b(x[id]);
  }
}

// ========== 256x128 GEMM, K=512, BK=32, depth-3 stage-ahead-2 vmcnt(3), 2 blocks/CU ==========
// A tiled CA=512; W row-major (N, KTOT). flags: 1=relu 2=elu+1 4=+res 8=+pe 32=QKV
template<int KTOT>
__global__ __launch_bounds__(512, 4) void gemm9_k(
    const u16* __restrict__ A, const u16* __restrict__ W,
    const float* __restrict__ bias, const float* __restrict__ bias2,
    const float* __restrict__ bias3,
    u16* __restrict__ out, const u16* __restrict__ resb,
    const float* __restrict__ peb,
    int N, int nN, int flags)
{
  constexpr int KT = KTOT >> 5;    // ktiles of 32
  __shared__ u16 As[3][8192];      // 256 rows x 32 cols
  __shared__ u16 Bs[3][4096];      // 128 rows x 32 cols
  const int tid = threadIdx.x;
  const int wave = tid >> 6, lane = tid & 63;
  const int wm = wave >> 1, wn = wave & 1;     // 4m x 2n waves
  const int c0 = lane >> 4, fro = lane & 15;
  const int sr = tid >> 2, sp = tid & 3;       // staging row(128-group), phys chunk

  const int nwg = gridDim.x;
  const int lin = blockIdx.x;
  const int swz = (lin & 7) * (nwg >> 3) + (lin >> 3);
  const int mb = swz / nN, nb = swz - mb * nN;
  const int m0 = mb << 8, n0 = nb << 7;

  const f32x4 zf = {0.f,0.f,0.f,0.f};
  f32x4 acc[4][4];
  #pragma unroll
  for (int i=0;i<4;++i)
    #pragma unroll
    for (int j=0;j<4;++j) acc[i][j] = zf;

  auto SA = [&](int t, int half){
    int row = (half << 7) + sr;
    int lc = sp ^ ((row >> 1) & 3);
    int grow = m0 + row;
    size_t ga = ((size_t)(grow >> 7) << 16) + ((size_t)t << 12)
              + ((grow & 127) << 5) + (lc << 3);
    gload16(A + ga, &As[t % 3][(half << 12) + (wave << 9)]);
  };
  auto SB = [&](int t){
    int lc = sp ^ ((sr >> 1) & 3);
    gload16(W + (size_t)(n0 + sr) * KTOT + (t << 5) + (lc << 3),
            &Bs[t % 3][wave << 9]);
  };
  auto STG = [&](int s){ SA(s, 0); SA(s, 1); SB(s); };

  auto CMP = [&](int s){
    int b = s % 3;
    bhalf8 af[4], bf[4];
    #pragma unroll
    for (int mt = 0; mt < 4; ++mt){
      int row = (wm << 6) + (mt << 4) + fro;
      int phys = c0 ^ ((row >> 1) & 3);
      af[mt] = *(const bhalf8*)&As[b][row * 32 + (phys << 3)];
    }
    #pragma unroll
    for (int nt = 0; nt < 4; ++nt){
      int row = (wn << 6) + (nt << 4) + fro;
      int phys = c0 ^ ((row >> 1) & 3);
      bf[nt] = *(const bhalf8*)&Bs[b][row * 32 + (phys << 3)];
    }
    // swapped operands: per-thread 4 consecutive output cols
    #pragma unroll
    for (int mt = 0; mt < 4; ++mt)
      #pragma unroll
      for (int nt = 0; nt < 4; ++nt)
        acc[mt][nt] = __builtin_amdgcn_mfma_f32_16x16x32_bf16(bf[nt], af[mt], acc[mt][nt], 0, 0, 0);
  };

  STG(0);
  if (KT > 1) STG(1);
  #pragma unroll
  for (int s = 0; s < KT; ++s){
    if (s + 1 >= KT) asm volatile("s_waitcnt vmcnt(0)" ::: "memory");
    else             asm volatile("s_waitcnt vmcnt(3)" ::: "memory");
    __builtin_amdgcn_sched_barrier(0);
    __builtin_amdgcn_s_barrier();
    __builtin_amdgcn_sched_barrier(0);
    if (s + 2 < KT) STG(s + 2);
    CMP(s);
  }

  // ---- epilogue: row = m0+(wm<<6)+(mt<<4)+fro, cols 4-consecutive ----
  const int th = n0 >> 9;
  #pragma unroll
  for (int mt = 0; mt < 4; ++mt){
    const int row = m0 + (wm << 6) + (mt << 4) + fro;
    const size_t prow = (size_t)(row & (S_LEN - 1)) * 512;
    #pragma unroll
    for (int nt = 0; nt < 4; ++nt){
      const int col = n0 + (wn << 6) + (nt << 4) + (c0 << 2);
      float v0 = acc[mt][nt][0], v1 = acc[mt][nt][1], v2 = acc[mt][nt][2], v3 = acc[mt][nt][3];
      if (flags & 32){
        const float* bp = (th == 0) ? bias : ((th == 1) ? bias2 : bias3);
        if (bp){ float4 b4 = *(const float4*)&bp[col & 511]; v0+=b4.x; v1+=b4.y; v2+=b4.z; v3+=b4.w; }
      } else {
        if (bias){ float4 b4 = *(const float4*)&bias[col]; v0+=b4.x; v1+=b4.y; v2+=b4.z; v3+=b4.w; }
      }
      if (flags & 4){
        uint2 rv = *(const uint2*)(resb + taddr(row, col, N));
        float rf[4]; unp4(rv, rf);
        v0 += rf[0]; v1 += rf[1]; v2 += rf[2]; v3 += rf[3];
      }
      if (flags & 8){
        float4 p4 = *(const float4*)&peb[prow + col];
        v0 += p4.x; v1 += p4.y; v2 += p4.z; v3 += p4.w;
      }
      if (flags & 1){
        v0 = fmaxf(v0, 0.f); v1 = fmaxf(v1, 0.f); v2 = fmaxf(v2, 0.f); v3 = fmaxf(v3, 0.f);
      }
      if ((flags & 2) && (!(flags & 32) || th < 2)){
        v0 = (v0 > 0.f) ? (v0 + 1.f) : __expf(v0);
        v1 = (v1 > 0.f) ? (v1 + 1.f) : __expf(v1);
        v2 = (v2 > 0.f) ? (v2 + 1.f) : __expf(v2);
        v3 = (v3 > 0.f) ? (v3 + 1.f) : __expf(v3);
      }
      uint2 pk; pk.x = cvtpk(v0, v1); pk.y = cvtpk(v2, v3);
      *(uint2*)(out + taddr(row, col, N)) = pk;
    }
  }
}

// ---------------- 128x(64*NWT) GEMM. 1-tap: 3-buf stage-ahead-2 vmcnt(4).
// 3-tap: virtual steps, stage-ahead-2, DA=(KS2?3:2), DB=3, vmcnt(2).
// NWT=1: 4m-waves of 32x64 (acc[2][4]); NWT=2: 2m x 2n waves of 64x64 (acc[4][4]).
template<int NTAPS, int KS1, int KS2, int NWT>
__global__ __launch_bounds__(256) void gemm_k(
    const u16* __restrict__ A, const u16* __restrict__ W,
    const u16* __restrict__ A2, const u16* __restrict__ W2,
    const float* __restrict__ bias, const float* __restrict__ bias2,
    const float* __restrict__ bias3,
    u16* __restrict__ out, const u16* __restrict__ resb,
    const float* __restrict__ peb, const float* __restrict__ den,
    int N, int CA, int CA2, int dil, int nN, int wbstride, int flags)
{
  constexpr bool MT   = (NTAPS == 3);
  constexpr int HALO  = MT ? 8 : 0;
  constexpr int AR    = MT ? 144 : 128;
  constexpr int DA    = MT ? ((KS2 > 0) ? 3 : 2) : 3;
  constexpr int DB    = 3;
  constexpr int K     = KS1 << 5;
  constexpr int K2    = KS2 << 5;
  constexpr int TOTAL = MT ? (3*KS1 + KS2) : (KS1 + KS2);
  constexpr int BC    = NWT << 6;          // B rows (output cols per block)
  constexpr int MFR   = (NWT == 2) ? 4 : 2; // m fragments per wave
  __shared__ u16 As[DA][AR*32];
  __shared__ u16 Bs[DB][BC*32];
  const int tid = threadIdx.x;
  const int wave = tid >> 6, lane = tid & 63;
  const int wm = (NWT == 2) ? (wave >> 1) : wave;
  const int wn = (NWT == 2) ? (wave & 1) : 0;
  const int wrow0 = wm * (MFR << 4);
  const int wcol0 = wn << 6;

  const int nwg = gridDim.x;
  const int lin = blockIdx.x;
  const int swz = (lin & 7) * (nwg >> 3) + (lin >> 3);
  const int mb = swz / nN, nb = swz - mb * nN;
  const int m0 = mb << 7, n0 = nb * BC;
  const bool bnd = (m0 & (S_LEN - 1)) == 0;

  const u16* Ae = (flags & 16) ? (A + (((size_t)(n0 & 511) >> 5) << 12)) : A;

  const int lr4 = lane >> 2, lc4 = lane & 3;
  const int c0 = lane >> 4, fro = lane & 15;

  const f32x4 zf = {0.f, 0.f, 0.f, 0.f};
  const bhalf8 zb = {0,0,0,0,0,0,0,0};
  f32x4 acc[MFR][4];
  #pragma unroll
  for (int i=0;i<MFR;++i)
    #pragma unroll
    for (int j=0;j<4;++j) acc[i][j] = zf;

  const u16* Wb = W + (size_t)(m0 >> 12) * (size_t)wbstride;
  const size_t abase  = (size_t)mb * ((size_t)CA  << 7);
  const size_t abase2 = (size_t)mb * ((size_t)CA2 << 7);

  auto STAGE_A = [&](int kb, int ab){
    const size_t tb = abase + ((size_t)kb << 12);
    #pragma unroll
    for (int half = 0; half < 2; ++half){
      int mrow = (wave << 5) + (half << 4) + lr4;
      int i = mrow + HALO;
      int cg = lc4 ^ ((i >> 1) & 3);
      gload16(Ae + tb + mrow*32 + (cg << 3), &As[ab][(HALO + (wave << 5) + (half << 4)) * 32]);
    }
    if (MT && wave == 0 && lane < 32){
      int j = lr4;
      int cg = lc4 ^ ((j >> 1) & 3);
      size_t hb_ = (mb ? abase - ((size_t)CA << 7) : abase) + ((size_t)kb << 12) + (120 + j)*32;
      gload16(Ae + hb_ + (cg << 3), &As[ab][0]);
    }
  };
  auto STAGE_A2 = [&](int t2, int ab){
    const size_t tb = abase2 + ((size_t)t2 << 12);
    #pragma unroll
    for (int half = 0; half < 2; ++half){
      int mrow = (wave << 5) + (half << 4) + lr4;
      int i = mrow + HALO;
      int cg = lc4 ^ ((i >> 1) & 3);
      gload16(A2 + tb + mrow*32 + (cg << 3), &As[ab][(HALO + (wave << 5) + (half << 4)) * 32]);
    }
  };
  auto STAGE_B = [&](const u16* Wt, size_t kstride, int kb, int bb){
    #pragma unroll
    for (int h = 0; h < NWT; ++h){
      int i = wave * (NWT << 4) + (h << 4) + lr4;
      int cg = lc4 ^ ((i >> 1) & 3);
      gload16(Wt + (size_t)(n0 + i) * kstride + (kb << 5) + (cg << 3),
              &Bs[bb][(wave * (NWT << 4) + (h << 4)) * 32]);
    }
  };
  auto DOMM = [&](int ab, int bb, int sh, bool mask){
    bhalf8 af[MFR], bf[4];
    #pragma unroll
    for (int mt = 0; mt < MFR; ++mt){
      int r8 = wrow0 + (mt << 4) + fro + HALO + sh;
      af[mt] = *(const bhalf8*)&As[ab][r8 * 32 + ((c0 ^ ((r8 >> 1) & 3)) << 3)];
    }
    if (MT && mask && bnd && wm == 0 && fro + sh < 0) af[0] = zb;
    #pragma unroll
    for (int nt = 0; nt < 4; ++nt){
      int rB = wcol0 + (nt << 4) + fro;
      bf[nt] = *(const bhalf8*)&Bs[bb][rB * 32 + ((c0 ^ ((rB >> 1) & 3)) << 3)];
    }
    #pragma unroll
    for (int mt = 0; mt < MFR; ++mt)
      #pragma unroll
      for (int nt = 0; nt < 4; ++nt)
        acc[mt][nt] = __builtin_amdgcn_mfma_f32_16x16x32_bf16(bf[nt], af[mt], acc[mt][nt], 0, 0, 0);
  };

  if constexpr (!MT){
    auto STG = [&](int s){
      int b = s % 3;
      if (s < KS1){ STAGE_A(s, b); STAGE_B(Wb, (size_t)K, s, b); }
      else if (KS2 > 0){ STAGE_A2(s - KS1, b); STAGE_B(W2, (size_t)K2, s - KS1, b); }
    };
    STG(0);
    if constexpr (TOTAL > 1) STG(1);
    #pragma unroll
    for (int s = 0; s < TOTAL; ++s){
      if (s + 1 >= TOTAL) asm volatile("s_waitcnt vmcnt(0)" ::: "memory");
      else                asm volatile("s_waitcnt vmcnt(4)" ::: "memory");
      __builtin_amdgcn_sched_barrier(0);
      __builtin_amdgcn_s_barrier();
      __builtin_amdgcn_sched_barrier(0);
      if (s + 2 < TOTAL) STG(s + 2);
      DOMM(s % 3, s % 3, 0, false);
    }
  } else {
    auto STG = [&](int s){
      if (s < 3*KS1){
        int kb = s / 3, tap = s % 3;
        if (tap == 0) STAGE_A(kb, kb % DA);
        STAGE_B(Wb + (size_t)tap * N * K, (size_t)K, kb, s % 3);
      } else if (KS2 > 0){
        int t2 = s - 3*KS1;
        STAGE_A2(t2, (KS1 + t2) % DA);
        STAGE_B(W2, (size_t)K2, t2, s % 3);
      }
    };
    STG(0);
    if constexpr (TOTAL > 1) STG(1);
    #pragma unroll
    for (int s = 0; s < TOTAL; ++s){
      if (s + 1 >= TOTAL) asm volatile("s_waitcnt vmcnt(0)" ::: "memory");
      else                asm volatile("s_waitcnt vmcnt(2)" ::: "memory");
      __builtin_amdgcn_sched_barrier(0);
      __builtin_amdgcn_s_barrier();
      __builtin_amdgcn_sched_barrier(0);
      if (s + 2 < TOTAL) STG(s + 2);
      if (s < 3*KS1) DOMM((s/3) % DA, s % 3, ((s%3) - 2) * dil, true);
      else           DOMM((KS1 + (s - 3*KS1)) % DA, s % 3, 0, false);
    }
  }

  const int mb_l = wrow0 + fro;
  const int cb_l = wcol0 + (c0 << 2);
  const int th = n0 >> 9;
  #pragma unroll
  for (int mt = 0; mt < MFR; ++mt){
    const int row = m0 + mb_l + (mt << 4);
    const size_t prow = (size_t)(row & (S_LEN - 1)) * 512;
    #pragma unroll
    for (int nt = 0; nt < 4; ++nt){
      const int col = n0 + cb_l + (nt << 4);
      float v0 = acc[mt][nt][0], v1 = acc[mt][nt][1], v2 = acc[mt][nt][2], v3 = acc[mt][nt][3];
      if (flags & 32){
        const float* bp = (th == 0) ? bias : ((th == 1) ? bias2 : bias3);
        if (bp){ float4 b4 = *(const float4*)&bp[col & 511]; v0+=b4.x; v1+=b4.y; v2+=b4.z; v3+=b4.w; }
      } else {
        if (bias) { float4 b4 = *(const float4*)&bias[col];  v0+=b4.x; v1+=b4.y; v2+=b4.z; v3+=b4.w; }
        if (bias2){ float4 b4 = *(const float4*)&bias2[col]; v0+=b4.x; v1+=b4.y; v2+=b4.z; v3+=b4.w; }
      }
      if (flags & 4){
        uint2 rv = *(const uint2*)(resb + taddr(row, col, N));
        float rf[4]; unp4(rv, rf);
        v0 += rf[0]; v1 += rf[1]; v2 += rf[2]; v3 += rf[3];
      }
      if (flags & 8){
        float4 p4 = *(const float4*)&peb[prow + col];
        v0 += p4.x; v1 += p4.y; v2 += p4.z; v3 += p4.w;
      }
      if (flags & 16){
        float d = fmaxf(den[((size_t)row << 3) + (col >> 6)], 1e-6f);
        float rd = 1.0f / d;
        v0 *= rd; v1 *= rd; v2 *= rd; v3 *= rd;
      }
      if (flags & 1){
        v0 = fmaxf(v0, 0.f); v1 = fmaxf(v1, 0.f); v2 = fmaxf(v2, 0.f); v3 = fmaxf(v3, 0.f);
      }
      if ((flags & 2) && (!(flags & 32) || th < 2)){
        v0 = (v0 > 0.f) ? (v0 + 1.f) : __expf(v0);
        v1 = (v1 > 0.f) ? (v1 + 1.f) : __expf(v1);
        v2 = (v2 > 0.f) ? (v2 + 1.f) : __expf(v2);
        v3 = (v3 > 0.f) ? (v3 + 1.f) : __expf(v3);
      }
      uint2 pk; pk.x = cvtpk(v0, v1); pk.y = cvtpk(v2, v3);
      *(uint2*)(out + taddr(row, col, N)) = pk;
    }
  }
}

// ---------------- linear attention: partial kv = sum_n kf (outer) v, ksum ----------------
// double-buffered LDS, issue-early/write-late (T14): 1 barrier per 16-row tile
__global__ __launch_bounds__(256) void kv_partial(
    const u16* __restrict__ qkv,
    float* __restrict__ kvp, float* __restrict__ ksp)
{
  const int bh = blockIdx.x;
  const int b = bh >> 3, h = bh & 7;
  const int ch = blockIdx.y;
  const int t = threadIdx.x;
  __shared__ u16 kfs[2][16][64];
  __shared__ u16 vs[2][16][64];
  float acc[4][4] = {{0.f}};
  float ks[4] = {0.f,0.f,0.f,0.f};
  const int d0 = (t >> 4) << 2;
  const int c0 = (t & 15) << 2;
  const int lr = t >> 4, lc = (t & 15) << 2;
  const int rowbase = (b << 12) + (ch << 9);
  const int ck = 512 + (h << 6) + lc;
  const int cv = 1024 + (h << 6) + lc;

  uint2 rk = *(const uint2*)(qkv + taddr(rowbase + lr, ck, 1536));
  uint2 rv = *(const uint2*)(qkv + taddr(rowbase + lr, cv, 1536));
  *(uint2*)&kfs[0][lr][lc] = rk;
  *(uint2*)&vs[0][lr][lc]  = rv;
  __syncthreads();
  int cur = 0;
  for (int g = 0; g < 32; ++g){
    if (g + 1 < 32){
      int r = rowbase + ((g + 1) << 4) + lr;
      rk = *(const uint2*)(qkv + taddr(r, ck, 1536));
      rv = *(const uint2*)(qkv + taddr(r, cv, 1536));
    }
    #pragma unroll
    for (int i = 0; i < 16; ++i){
      float kv4[4], vv4[4];
      unp4(*(const uint2*)&kfs[cur][i][d0], kv4);
      unp4(*(const uint2*)&vs[cur][i][c0], vv4);
      #pragma unroll
      for (int j=0;j<4;++j)
        #pragma unroll
        for (int k2=0;k2<4;++k2) acc[j][k2] += kv4[j]*vv4[k2];
      if ((t & 15) == 0){
        #pragma unroll
        for (int j=0;j<4;++j) ks[j] += kv4[j];
      }
    }
    if (g + 1 < 32){
      *(uint2*)&kfs[cur ^ 1][lr][lc] = rk;
      *(uint2*)&vs[cur ^ 1][lr][lc]  = rv;
    }
    __syncthreads();
    cur ^= 1;
  }
  float* dst = kvp + ((size_t)(bh << 3) + ch) * 4096;
  #pragma unroll
  for (int j=0;j<4;++j)
    #pragma unroll
    for (int k2=0;k2<4;++k2) dst[(d0+j)*64 + (c0+k2)] = acc[j][k2];
  if ((t & 15) == 0){
    float* kd = ksp + ((size_t)(bh << 3) + ch) * 64;
    #pragma unroll
    for (int j=0;j<4;++j) kd[d0+j] = ks[j];
  }
}

__global__ __launch_bounds__(256) void kvred_k(
    const float* __restrict__ kvp, const float* __restrict__ ksp,
    float* __restrict__ kvf, float* __restrict__ ksf)
{
  int bh = blockIdx.x, t = threadIdx.x;
  for (int e = t; e < 4096; e += 256){
    float s = 0.f;
    #pragma unroll
    for (int ch = 0; ch < 8; ++ch) s += kvp[((size_t)(bh<<3)+ch)*4096 + e];
    kvf[(size_t)bh*4096 + e] = s;
  }
  if (t < 64){
    float s = 0.f;
    #pragma unroll
    for (int ch = 0; ch < 8; ++ch) s += ksp[((size_t)(bh<<3)+ch)*64 + t];
    ksf[bh*64 + t] = s;
  }
}

// merged: blocks [0,1024) compute den; blocks [1024,3072) pack wbd
__global__ __launch_bounds__(256) void denpack_k(const u16* __restrict__ qkv,
    const float* __restrict__ ksf, float* __restrict__ den,
    const float* __restrict__ kvf, u16* __restrict__ wbd)
{
  int bid = blockIdx.x;
  if (bid < 1024){
    int id = bid*256 + threadIdx.x;
    int r = id >> 3, h = id & 7;
    int b = r >> 12;
    const float* ks = ksf + ((b<<3)+h)*64;
    float s = 0.f;
    for (int d = 0; d < 64; d += 8){
      uint4 vq = *(const uint4*)(qkv + taddr(r, (h << 6) + d, 1536));
      float f[8]; unp8(vq, f);
      #pragma unroll
      for (int j=0;j<8;++j) s += f[j]*ks[d+j];
    }
    den[id] = s;
  } else {
    int id = (bid - 1024)*256 + threadIdx.x;   // 8*512*128
    int b = id >> 16;
    int n = (id >> 7) & 511, j = id & 127;
    float v = 0.f;
    if ((j >> 6) == ((n >> 6) & 1))
      v = kvf[((size_t)((b<<3)+(n>>6)))*4096 + (j & 63)*64 + (n & 63)];
    wbd[id] = f2b(v);
  }
}

__global__ __launch_bounds__(256) void ln_k(const u16* __restrict__ in,
    const float* __restrict__ g, const float* __restrict__ beta, u16* __restrict__ out)
{
  int wave = threadIdx.x >> 6, lane = threadIdx.x & 63;
  int row = blockIdx.x*4 + wave;
  size_t ad = taddr(row, lane*8, 512);
  uint4 pv = *(const uint4*)(in + ad);
  float f[8]; unp8(pv, f);
  float s = 0.f, ss = 0.f;
  #pragma unroll
  for (int i=0;i<8;++i){ s += f[i]; ss += f[i]*f[i]; }
  for (int m=1;m<64;m<<=1){ s += __shfl_xor(s,m); ss += __shfl_xor(ss,m); }
  float mean = s * (1.f/512.f);
  float var = ss * (1.f/512.f) - mean*mean;
  float rstd = rsqrtf(fmaxf(var, 0.f) + 1e-5f);
  u16 o[8];
  #pragma unroll
  for (int i=0;i<8;++i){
    int c = lane*8 + i;
    o[i] = f2b((f[i]-mean)*rstd*g[c] + beta[c]);
  }
  *(uint4*)(out + ad) = *(uint4*)o;
}

// ------- fused LN + mean-pool + dot W_out
__global__ __launch_bounds__(256) void pool1_k(const u16* __restrict__ hb,
    const float* __restrict__ wout, const float* __restrict__ g,
    const float* __restrict__ beta, float* __restrict__ part)
{
  int b = blockIdx.x >> 6, ch = blockIdx.x & 63;
  int t = threadIdx.x;
  __shared__ float ws[512];
  __shared__ float red[256];
  __shared__ float S2[2];
  float a0 = 0.f, a1 = 0.f;
  for (int i = t; i < 512; i += 256){
    float w = wout[i];
    float gw = w * g[i];
    ws[i] = gw;
    a0 += gw;
    a1 += w * beta[i];
  }
  red[t] = a0; __syncthreads();
  for (int k2=128;k2;k2>>=1){ if (t<k2) red[t]+=red[t+k2]; __syncthreads(); }
  if (!t) S2[0] = red[0];
  __syncthreads();
  red[t] = a1; __syncthreads();
  for (int k2=128;k2;k2>>=1){ if (t<k2) red[t]+=red[t+k2]; __syncthreads(); }
  if (!t) S2[1] = red[0];
  __syncthreads();
  const float Sgw = S2[0], Sbw = S2[1];

  int r = (b << 12) + (ch << 6) + (t >> 2);
  int c0 = (t & 3) << 7;
  float sd = 0.f, s1 = 0.f, s2 = 0.f;
  for (int i = 0; i < 128; i += 8){
    uint4 v = *(const uint4*)(hb + taddr(r, c0 + i, 512));
    float f[8]; unp8(v, f);
    #pragma unroll
    for (int j=0;j<8;++j){ float x = f[j]; sd += x*ws[c0+i+j]; s1 += x; s2 += x*x; }
  }
  sd += __shfl_xor(sd,1); s1 += __shfl_xor(s1,1); s2 += __shfl_xor(s2,1);
  sd += __shfl_xor(sd,2); s1 += __shfl_xor(s1,2); s2 += __shfl_xor(s2,2);
  float mean = s1 * (1.f/512.f);
  float var  = s2 * (1.f/512.f) - mean*mean;
  float rstd = rsqrtf(fmaxf(var, 0.f) + 1e-5f);
  float rowv = rstd * (sd - mean * Sgw) + Sbw;
  red[t] = ((t & 3) == 0) ? rowv : 0.f;
  __syncthreads();
  for (int k2=128;k2;k2>>=1){ if (t<k2) red[t]+=red[t+k2]; __syncthreads(); }
  if (!t) part[blockIdx.x] = red[0];
}

__global__ __launch_bounds__(64) void pool2_k(const float* __restrict__ part,
    const float* __restrict__ bout, float* __restrict__ out)
{
  int b = blockIdx.x, t = threadIdx.x;
  float s = part[(b << 6) + t];
  for (int m=1;m<64;m<<=1) s += __shfl_xor(s,m);
  if (!t) out[b] = s * (1.f/4096.f) + bout[0];
}

// =========================================================================
extern "C" void kernel_launch(void* const* d_in, const int* in_sizes, int n_in,
                              void* d_out, int out_size, void* d_ws, size_t ws_size,
                              hipStream_t stream)
{
  (void)in_sizes; (void)n_in; (void)out_size; (void)ws_size;
  const float* x    = (const float*)d_in[0];
  const float* W_in = (const float*)d_in[1];
  const float* b_in = (const float*)d_in[2];
  const float* c1w0 = (const float*)d_in[3];
  const float* c1b0 = (const float*)d_in[4];
  const float* c2w0 = (const float*)d_in[5];
  const float* c2b0 = (const float*)d_in[6];
  const float* dsw0 = (const float*)d_in[7];
  const float* dsb0 = (const float*)d_in[8];
  const float* c1w1 = (const float*)d_in[9];
  const float* c1b1 = (const float*)d_in[10];
  const float* c2w1 = (const float*)d_in[11];
  const float* c2b1 = (const float*)d_in[12];
  const float* c1w2 = (const float*)d_in[13];
  const float* c1b2 = (const float*)d_in[14];
  const float* c2w2 = (const float*)d_in[15];
  const float* c2b2 = (const float*)d_in[16];
  const float* dsw2 = (const float*)d_in[17];
  const float* dsb2 = (const float*)d_in[18];
  const float* W_tcn= (const float*)d_in[19];
  const float* b_tcn= (const float*)d_in[20];
  const float* Wq   = (const float*)d_in[21];
  const float* Wk   = (const float*)d_in[22];
  const float* Wv   = (const float*)d_in[23];
  const float* Wo   = (const float*)d_in[24];
  const float* bq   = (const float*)d_in[25];
  const float* bk   = (const float*)d_in[26];
  const float* bv   = (const float*)d_in[27];
  const float* bo   = (const float*)d_in[28];
  const float* lnb  = (const float*)d_in[29];
  const float* lng  = (const float*)d_in[30];
  const float* W_out= (const float*)d_in[31];
  const float* b_out= (const float*)d_in[32];

  char* base = (char*)d_ws;
  size_t off = 0;
  auto alloc = [&](size_t bytes) -> void* {
    void* p = base + off;
    off += (bytes + 255) & ~(size_t)255;
    return p;
  };
  u16* WB   = (u16*)alloc(4816896ull*2);
  u16* wbd  = (u16*)alloc(8ull*512*128*2);
  float* peb= (float*)alloc(4096ull*512*4);
  float* den= (float*)alloc(32768ull*8*4);
  float* kvp= (float*)alloc(512ull*4096*4);
  float* ksp= (float*)alloc(512ull*64*4);
  float* kvf= (float*)alloc(64ull*4096*4);
  float* ksf= (float*)alloc(64ull*64*4);
  float* part=(float*)alloc(512*4);
  u16* hb   = (u16*)alloc(32768ull*512*2);
  char* qkvR= (char*)alloc(32768ull*1536*2);
  u16* atto = (u16*)alloc(32768ull*512*2);

  u16* qkvb = (u16*)qkvR;
  u16* xb   = (u16*)(qkvR);
  u16* t1b  = (u16*)(qkvR + 4194304);
  u16* t2b  = (u16*)(qkvR + 20971520);
  u16* t3b  = (u16*)(qkvR + 37748736);
  u16* o1b  = atto;

  unsigned wo_ = 0;
  auto wseg = [&](unsigned e){ unsigned o = wo_; wo_ += e; return o; };
  unsigned oWin  = wseg(512*64);
  unsigned oC1w0 = wseg(3*256*512);
  unsigned oC2w0 = wseg(3*256*256);
  unsigned oDs0  = wseg(256*512);
  unsigned oC1w1 = wseg(3*256*256);
  unsigned oC2w1 = wseg(3*256*256);
  unsigned oC1w2 = wseg(3*512*256);
  unsigned oC2w2 = wseg(3*512*512);
  unsigned oDs2  = wseg(512*256);
  unsigned oWtcn = wseg(512*512);
  unsigned oQKV  = wseg(2*1536*512);
  unsigned oWo   = wseg(2*512*512);

  PrepArgs pa;
  int si = 0;
  auto seg = [&](const float* s, int N, int K, int sn, int sk, unsigned o){
    pa.src[si]=s; pa.N[si]=N; pa.K[si]=K; pa.sn[si]=sn; pa.sk[si]=sk; pa.off[si]=o; ++si;
  };
  seg(W_in, 512, 64, 1, 512, oWin);
  for (int t=0;t<3;++t) seg(c1w0 + t, 256, 512, 1536, 3, oC1w0 + t*131072);
  for (int t=0;t<3;++t) seg(c2w0 + t, 256, 256,  768, 3, oC2w0 + t*65536);
  seg(dsw0, 256, 512, 512, 1, oDs0);
  for (int t=0;t<3;++t) seg(c1w1 + t, 256, 256,  768, 3, oC1w1 + t*65536);
  for (int t=0;t<3;++t) seg(c2w1 + t, 256, 256,  768, 3, oC2w1 + t*65536);
  for (int t=0;t<3;++t) seg(c1w2 + t, 512, 256,  768, 3, oC1w2 + t*131072);
  for (int t=0;t<3;++t) seg(c2w2 + t, 512, 512, 1536, 3, oC2w2 + t*262144);
  seg(dsw2, 512, 256, 256, 1, oDs2);
  seg(W_tcn, 512, 512, 1, 512, oWtcn);
  for (int l=0;l<2;++l){
    seg(Wq + l*262144, 512, 512, 1, 512, oQKV + l*786432 + 0);
    seg(Wk + l*262144, 512, 512, 1, 512, oQKV + l*786432 + 262144);
    seg(Wv + l*262144, 512, 512, 1, 512, oQKV + l*786432 + 524288);
  }
  for (int l=0;l<2;++l) seg(Wo + l*262144, 512, 512, 1, 512, oWo + l*262144);

  // merged prep: weights | PE | x-convert
  prep_all<<<dim3(256*NSEG + 4096 + 8192), 256, 0, stream>>>(pa, WB, peb, x, xb);

  const int RELU=1, ELU1=2, RES=4, PE=8, DIV=16, QKV=32;
  // 3-tap convs: 128x64 tiles (NWT=1); 1-tap small-K: 128x128 (NWT=2)
  auto gemm = [&](const u16* A, const u16* W, const u16* A2, const u16* W2,
                  const float* b1, const float* b2, const float* b3,
                  u16* out, const u16* resb,
                  int K, int K2, int N, int CA, int CA2, int ntaps,
                  int dil, int wbs, int flags){
    if (ntaps == 3){
      int nN = N >> 6;
      dim3 grid(256 * nN);
      if (K == 512 && K2 == 0)
        gemm_k<3,16,0,1><<<grid, 256, 0, stream>>>(A, W, A2, W2, b1, b2, b3, out, resb,
                                                   peb, den, N, CA, CA2, dil, nN, wbs, flags);
      else if (K == 256 && K2 == 512)
        gemm_k<3,8,16,1><<<grid, 256, 0, stream>>>(A, W, A2, W2, b1, b2, b3, out, resb,
                                                   peb, den, N, CA, CA2, dil, nN, wbs, flags);
      else if (K == 256 && K2 == 0)
        gemm_k<3,8,0,1><<<grid, 256, 0, stream>>>(A, W, A2, W2, b1, b2, b3, out, resb,
                                                  peb, den, N, CA, CA2, dil, nN, wbs, flags);
      else
        gemm_k<3,16,8,1><<<grid, 256, 0, stream>>>(A, W, A2, W2, b1, b2, b3, out, resb,
                                                   peb, den, N, CA, CA2, dil, nN, wbs, flags);
    } else {
      int nN = N >> 7;
      dim3 grid(256 * nN);
      if (K == 64)
        gemm_k<1,2,0,2><<<grid, 256, 0, stream>>>(A, W, A2, W2, b1, b2, b3, out, resb,
                                                  peb, den, N, CA, CA2, dil, nN, wbs, flags);
      else
        gemm_k<1,4,0,2><<<grid, 256, 0, stream>>>(A, W, A2, W2, b1, b2, b3, out, resb,
                                                  peb, den, N, CA, CA2, dil, nN, wbs, flags);
    }
  };
  // 256x128 2-blocks/CU path for K=512 1-tap GEMMs (A tiled CA=512, W row-major K=512)
  auto gemm9 = [&](const u16* A, const u16* W, const float* b1, const float* b2,
                   const float* b3, u16* out, const u16* resb, int N, int flags){
    int nN = N >> 7;
    gemm9_k<512><<<dim3(128 * nN), 512, 0, stream>>>(A, W, b1, b2, b3, out, resb,
                                                     peb, N, nN, flags);
  };

  // input projection: h = x @ W_in + b_in
  gemm(xb, WB + oWin, nullptr, nullptr, b_in, nullptr, nullptr, hb, nullptr,
       64, 0, 512, 64, 0, 1, 1, 0, 0);
  // TCN block 0 (dil=1, 512->256, fused ds)
  gemm(hb,  WB + oC1w0, nullptr, nullptr, c1b0, nullptr, nullptr, o1b, nullptr,
       512, 0, 256, 512, 0, 3, 1, 0, RELU);
  gemm(o1b, WB + oC2w0, hb, WB + oDs0, c2b0, dsb0, nullptr, t1b, nullptr,
       256, 512, 256, 256, 512, 3, 1, 0, RELU);
  // TCN block 1 (dil=2, 256->256, identity residual)
  gemm(t1b, WB + oC1w1, nullptr, nullptr, c1b1, nullptr, nullptr, o1b, nullptr,
       256, 0, 256, 256, 0, 3, 2, 0, RELU);
  gemm(o1b, WB + oC2w1, nullptr, nullptr, c2b1, nullptr, nullptr, t2b, t1b,
       256, 0, 256, 256, 0, 3, 2, 0, RELU|RES);
  // TCN block 2 (dil=4, 256->512, fused ds)
  gemm(t2b, WB + oC1w2, nullptr, nullptr, c1b2, nullptr, nullptr, o1b, nullptr,
       256, 0, 512, 256, 0, 3, 4, 0, RELU);
  gemm(o1b, WB + oC2w2, t2b, WB + oDs2, c2b2, dsb2, nullptr, t3b, nullptr,
       512, 256, 512, 512, 256, 3, 4, 0, RELU);
  // h = h + t3 @ W_tcn + b_tcn + pe   (256x128 path, in-place residual)
  gemm9(t3b, WB + oWtcn, b_tcn, nullptr, nullptr, hb, hb, 512, RES|PE);

  for (int l = 0; l < 2; ++l){
    // fused QKV: qkvb = [elu(q)+1 | elu(k)+1 | v]  (N=1536)
    gemm9(hb, WB + oQKV + l*786432, bq + l*512, bk + l*512, bv + l*512,
          qkvb, nullptr, 1536, ELU1|QKV);
    kv_partial<<<dim3(64, 8), 256, 0, stream>>>(qkvb, kvp, ksp);
    kvred_k<<<64, 256, 0, stream>>>(kvp, ksp, kvf, ksf);
    denpack_k<<<3072, 256, 0, stream>>>(qkvb, ksf, den, kvf, wbd);
    // atto = (qf @ kv) / den   (block-diag, K=128 window per n-tile)
    gemm(qkvb, wbd, nullptr, nullptr, nullptr, nullptr, nullptr, atto, nullptr,
         128, 0, 512, 1536, 0, 1, 1, 512*128, DIV);
    // h = h + atto @ Wo + bo  (256x128 path, in-place residual)
    gemm9(atto, WB + oWo + l*262144, bo + l*512, nullptr, nullptr, hb, hb, 512, RES);
    if (l == 0)
      ln_k<<<8192, 256, 0, stream>>>(hb, lng, lnb, hb);
  }

  pool1_k<<<512, 256, 0, stream>>>(hb, W_out, lng + 512, lnb + 512, part);
  pool2_k<<<8, 64, 0, stream>>>(part, b_out, (float*)d_out);
}